// Round 2
// baseline (743.323 us; speedup 1.0000x reference)
//
#include <hip/hip_runtime.h>

// Problem constants
constexpr int kB = 64, kN = 128, kRIN = 32, kROUT = 64, kDEMB = 64;
constexpr int kFE = 16, kE = 65536, kNTOT = 8192;
constexpr int kRF = 262144;   // B*N*RIN random floats per iteration

// ---------------- threefry2x32 (JAX-exact, 20 rounds) ----------------
__host__ __device__ __forceinline__ void tf_round(unsigned& x0, unsigned& x1, int r) {
  x0 += x1;
  x1 = (x1 << r) | (x1 >> (32 - r));
  x1 ^= x0;
}
__host__ __device__ __forceinline__ void tf2x32(unsigned k0, unsigned k1,
                                                unsigned& x0, unsigned& x1) {
  unsigned ks2 = k0 ^ k1 ^ 0x1BD11BDAu;
  x0 += k0; x1 += k1;
  tf_round(x0,x1,13); tf_round(x0,x1,15); tf_round(x0,x1,26); tf_round(x0,x1,6);
  x0 += k1; x1 += ks2 + 1u;
  tf_round(x0,x1,17); tf_round(x0,x1,29); tf_round(x0,x1,16); tf_round(x0,x1,24);
  x0 += ks2; x1 += k0 + 2u;
  tf_round(x0,x1,13); tf_round(x0,x1,15); tf_round(x0,x1,26); tf_round(x0,x1,6);
  x0 += k0; x1 += k1 + 3u;
  tf_round(x0,x1,17); tf_round(x0,x1,29); tf_round(x0,x1,16); tf_round(x0,x1,24);
  x0 += k1; x1 += ks2 + 4u;
  tf_round(x0,x1,13); tf_round(x0,x1,15); tf_round(x0,x1,26); tf_round(x0,x1,6);
  x0 += ks2; x1 += k0 + 5u;
}

// bits -> N(0,1), replicating jax.random.normal f32 path:
// u = max(lo, ((bits>>9|1.0f)-1) * 2.0f + lo), lo=nextafter(-1,0)
// normal = sqrt(2) * erfinv(u)  (Giles/XLA ErfInv32 polynomial)
__device__ __forceinline__ float bits_to_normal(unsigned bits) {
  float f = __uint_as_float((bits >> 9) | 0x3f800000u) - 1.0f;  // [0,1)
  const float LO = -0.99999994f;
  float u = fmaf(f, 2.0f, LO);
  u = fmaxf(u, LO);
  float w = -log1pf(-u * u);
  float p;
  if (w < 5.0f) {
    w -= 2.5f;
    p = 2.81022636e-08f;
    p = fmaf(p, w, 3.43273939e-07f);
    p = fmaf(p, w, -3.5233877e-06f);
    p = fmaf(p, w, -4.39150654e-06f);
    p = fmaf(p, w, 0.00021858087f);
    p = fmaf(p, w, -0.00125372503f);
    p = fmaf(p, w, -0.00417768164f);
    p = fmaf(p, w, 0.246640727f);
    p = fmaf(p, w, 1.50140941f);
  } else {
    w = sqrtf(w) - 3.0f;
    p = -0.000200214257f;
    p = fmaf(p, w, 0.000100950558f);
    p = fmaf(p, w, 0.00134934322f);
    p = fmaf(p, w, -0.00367342844f);
    p = fmaf(p, w, 0.00573950773f);
    p = fmaf(p, w, -0.0076224613f);
    p = fmaf(p, w, 0.00943887047f);
    p = fmaf(p, w, 1.00167406f);
    p = fmaf(p, w, 2.83297682f);
  }
  return 1.41421356f * (p * u);
}

// ---------------- edge kernel: agg[dst] += relu(x[src]@Wm + ef@We) ----------------
// One wave per 32 edges; lane = output dim j; Wm/We columns held in registers.
// x-row read via wave-uniform float4 loads (single L2 transaction, broadcast).
template <int K>
__global__ __launch_bounds__(256) void edge_kern(
    const float* __restrict__ xA, const int* __restrict__ eiA,
    const float* __restrict__ efA, float* __restrict__ aggA,
    const float* __restrict__ xB, const int* __restrict__ eiB,
    const float* __restrict__ efB, float* __restrict__ aggB,
    const float* __restrict__ Wm, const float* __restrict__ We) {
  int lane = threadIdx.x & 63;
  int wv = blockIdx.x * 4 + (threadIdx.x >> 6);  // 0..4095
  const float* x; const int* ei; const float* ef; float* agg;
  if (wv < 2048) { x = xA; ei = eiA; ef = efA; agg = aggA; }
  else { x = xB; ei = eiB; ef = efB; agg = aggB; wv -= 2048; }
  float wm[K];
#pragma unroll
  for (int k = 0; k < K; ++k) wm[k] = Wm[k * 64 + lane];
  float we[16];
#pragma unroll
  for (int f = 0; f < 16; ++f) we[f] = We[f * 64 + lane];
  int e0 = wv * 32;
  for (int e = e0; e < e0 + 32; ++e) {
    int src = ei[e];
    int dst = ei[kE + e];
    const float4* xr = reinterpret_cast<const float4*>(x + (size_t)src * K);
    float acc = 0.f;
#pragma unroll
    for (int k4 = 0; k4 < K / 4; ++k4) {
      float4 v = xr[k4];
      acc = fmaf(v.x, wm[4 * k4 + 0], acc);
      acc = fmaf(v.y, wm[4 * k4 + 1], acc);
      acc = fmaf(v.z, wm[4 * k4 + 2], acc);
      acc = fmaf(v.w, wm[4 * k4 + 3], acc);
    }
    const float4* er = reinterpret_cast<const float4*>(ef + (size_t)e * 16);
#pragma unroll
    for (int f4 = 0; f4 < 4; ++f4) {
      float4 v = er[f4];
      acc = fmaf(v.x, we[4 * f4 + 0], acc);
      acc = fmaf(v.y, we[4 * f4 + 1], acc);
      acc = fmaf(v.z, we[4 * f4 + 2], acc);
      acc = fmaf(v.w, we[4 * f4 + 3], acc);
    }
    float msg = fmaxf(acc, 0.f);
    unsafeAtomicAdd(agg + (size_t)dst * 64 + lane, msg);
  }
}

// ---------------- gnn1 node kernel: h = relu(x@Ws + agg + b) ----------------
__global__ __launch_bounds__(256) void node1_kern(
    const float* __restrict__ xR, const float* __restrict__ aggR, float* __restrict__ hR,
    const float* __restrict__ xP, const float* __restrict__ aggP, float* __restrict__ hP,
    const float* __restrict__ Ws, const float* __restrict__ bias) {
  int lane = threadIdx.x & 63;
  int wv = blockIdx.x * 4 + (threadIdx.x >> 6);  // 0..1023
  float wcol[64];
#pragma unroll
  for (int k = 0; k < 64; ++k) wcol[k] = Ws[k * 64 + lane];
  float bv = bias[lane];
  const float* x; const float* agg; float* h; int base;
  if (wv < 512) { x = xR; agg = aggR; h = hR; base = wv * 16; }
  else { x = xP; agg = aggP; h = hP; base = (wv - 512) * 16; }
  for (int n = base; n < base + 16; ++n) {
    float acc = agg[(size_t)n * 64 + lane] + bv;
    const float4* xr = reinterpret_cast<const float4*>(x + (size_t)n * 64);
#pragma unroll
    for (int k4 = 0; k4 < 16; ++k4) {
      float4 v = xr[k4];
      acc = fmaf(v.x, wcol[4 * k4 + 0], acc);
      acc = fmaf(v.y, wcol[4 * k4 + 1], acc);
      acc = fmaf(v.z, wcol[4 * k4 + 2], acc);
      acc = fmaf(v.w, wcol[4 * k4 + 3], acc);
    }
    h[(size_t)n * 64 + lane] = fmaxf(acc, 0.f);
  }
}

// ---------------- M_hat[b,r,p] = sum_d h_r[b,r,d]*h_p[b,p,d] ----------------
// 512 blocks (batch x 8 r-chunks of 16), 64 threads, 8r x 4p per thread.
__global__ __launch_bounds__(64) void mhat_kern(const float* __restrict__ hR,
                                                const float* __restrict__ hP,
                                                float* __restrict__ Mhat) {
  __shared__ float hr[16][66];
  __shared__ float hp[128][66];
  int b = blockIdx.x >> 3;
  int r0 = (blockIdx.x & 7) * 16;
  int t = threadIdx.x;
  const float* hrG = hR + ((size_t)b * 128 + r0) * 64;
#pragma unroll
  for (int s = 0; s < 16; ++s) { int i = t + 64 * s; hr[i >> 6][i & 63] = hrG[i]; }
  const float* hpG = hP + (size_t)b * 128 * 64;
#pragma unroll 8
  for (int s = 0; s < 128; ++s) { int i = t + 64 * s; hp[i >> 6][i & 63] = hpG[i]; }
  __syncthreads();
  int tx = t & 31;   // p = tx + 32*i
  int ty = t >> 5;   // r = r0 + ty + 2*ii
  float acc[8][4] = {};
  for (int d = 0; d < 64; ++d) {
    float a[8], bb[4];
#pragma unroll
    for (int ii = 0; ii < 8; ++ii) a[ii] = hr[ty + 2 * ii][d];
#pragma unroll
    for (int i = 0; i < 4; ++i) bb[i] = hp[tx + 32 * i][d];
#pragma unroll
    for (int ii = 0; ii < 8; ++ii)
#pragma unroll
      for (int i = 0; i < 4; ++i) acc[ii][i] = fmaf(a[ii], bb[i], acc[ii][i]);
  }
  float* outp = Mhat + ((size_t)b * 128 + r0) * 128;
#pragma unroll
  for (int ii = 0; ii < 8; ++ii)
#pragma unroll
    for (int i = 0; i < 4; ++i)
      outp[(size_t)(ty + 2 * ii) * 128 + tx + 32 * i] = acc[ii][i];
}

// ---------------- softmax rows of 128 (+ fused threefry RNG blocks) ----------------
// RNG: JAX partitionable mode — out[i] = x0 ^ x1 of threefry2x32(key, (0, i))
__global__ __launch_bounds__(256) void softmax_rng_kern(
    const float* __restrict__ Mhat, float* __restrict__ Mout, float* __restrict__ outDst,
    float* __restrict__ rf, unsigned fk0, unsigned fk1) {
  if (blockIdx.x < 2048) {
    int lane = threadIdx.x & 63;
    int row = blockIdx.x * 4 + (threadIdx.x >> 6);
    const float2* src = reinterpret_cast<const float2*>(Mhat + (size_t)row * 128);
    float2 v = src[lane];
    float mx = fmaxf(v.x, v.y);
#pragma unroll
    for (int o = 32; o > 0; o >>= 1) mx = fmaxf(mx, __shfl_xor(mx, o));
    float e0 = __expf(v.x - mx), e1 = __expf(v.y - mx);
    float s = e0 + e1;
#pragma unroll
    for (int o = 32; o > 0; o >>= 1) s += __shfl_xor(s, o);
    float inv = 1.0f / s;
    float2 r2; r2.x = e0 * inv; r2.y = e1 * inv;
    if (Mout)  reinterpret_cast<float2*>(Mout + (size_t)row * 128)[lane] = r2;
    if (outDst) reinterpret_cast<float2*>(outDst + (size_t)row * 128)[lane] = r2;
  } else {
    int ti = (blockIdx.x - 2048) * 256 + threadIdx.x;  // 0..16383
#pragma unroll
    for (int q = 0; q < 16; ++q) {
      unsigned i = (unsigned)ti + q * 16384u;   // 0..262143, coalesced
      unsigned x0 = 0u, x1 = i;                 // counter (hi, lo) = (0, i)
      tf2x32(fk0, fk1, x0, x1);
      rf[i] = bits_to_normal(x0 ^ x1);
    }
  }
}

// ---------------- rf_p[b,p,i] = sum_r M[b,r,p]*rf_r[b,r,i]  (+ agg zeroing blocks) ----
__global__ __launch_bounds__(256) void rfp_zero_kern(
    const float* __restrict__ M, const float* __restrict__ rf,
    float* __restrict__ rfp, float* __restrict__ aggz) {
  if (blockIdx.x < 64) {
    __shared__ float rr[128][32];
    int b = blockIdx.x;
    int t = threadIdx.x;
    const float* rfG = rf + (size_t)b * 128 * 32;
#pragma unroll
    for (int s = 0; s < 16; ++s) { int i = t + 256 * s; rr[i >> 5][i & 31] = rfG[i]; }
    __syncthreads();
    int p = t >> 1, hf = t & 1;
    float acc[16] = {};
    const float* Mb = M + (size_t)b * 16384 + p;
    for (int r = 0; r < 128; ++r) {
      float m = Mb[(size_t)r * 128];
#pragma unroll
      for (int i = 0; i < 16; ++i) acc[i] = fmaf(m, rr[r][hf * 16 + i], acc[i]);
    }
    float4* dst = reinterpret_cast<float4*>(rfp + ((size_t)b * 128 + p) * 32 + hf * 16);
    dst[0] = make_float4(acc[0], acc[1], acc[2], acc[3]);
    dst[1] = make_float4(acc[4], acc[5], acc[6], acc[7]);
    dst[2] = make_float4(acc[8], acc[9], acc[10], acc[11]);
    dst[3] = make_float4(acc[12], acc[13], acc[14], acc[15]);
  } else {
    int t = (blockIdx.x - 64) * 256 + threadIdx.x;  // 16384 threads
    float4 z4 = make_float4(0.f, 0.f, 0.f, 0.f);
    float4* z = reinterpret_cast<float4*>(aggz);    // zeros both aggs (contiguous, 1M floats)
#pragma unroll
    for (int s = 0; s < 16; ++s) z[t + s * 16384] = z4;
  }
}

// ---------------- gnn2 node + @W1 fusion: u = relu(rf@Ws2 + agg + b2g) @ W1 (+b1 for r) ----
__global__ __launch_bounds__(256) void node2u_kern(
    const float* __restrict__ rfR, const float* __restrict__ aggR, float* __restrict__ uR,
    const float* __restrict__ rfP, const float* __restrict__ aggP, float* __restrict__ uP,
    const float* __restrict__ Ws2, const float* __restrict__ b2g,
    const float* __restrict__ W1, const float* __restrict__ b1) {
  __shared__ float ost[4][64];   // wave-private o-row staging
  int lane = threadIdx.x & 63;
  int wl = threadIdx.x >> 6;
  int wv = blockIdx.x * 4 + wl;  // 0..1023
  float ws2[32];
#pragma unroll
  for (int k = 0; k < 32; ++k) ws2[k] = Ws2[k * 64 + lane];
  float w1c[64];
#pragma unroll
  for (int k = 0; k < 64; ++k) w1c[k] = W1[k * 64 + lane];
  float bgv = b2g[lane];
  const float* rf; const float* agg; float* u; float uinit; int base;
  if (wv < 512) { rf = rfR; agg = aggR; u = uR; base = wv * 16; uinit = b1[lane]; }
  else { rf = rfP; agg = aggP; u = uP; base = (wv - 512) * 16; uinit = 0.f; }
  for (int n = base; n < base + 16; ++n) {
    float acc = agg[(size_t)n * 64 + lane] + bgv;
    const float4* xr = reinterpret_cast<const float4*>(rf + (size_t)n * 32);
#pragma unroll
    for (int k4 = 0; k4 < 8; ++k4) {
      float4 v = xr[k4];
      acc = fmaf(v.x, ws2[4 * k4 + 0], acc);
      acc = fmaf(v.y, ws2[4 * k4 + 1], acc);
      acc = fmaf(v.z, ws2[4 * k4 + 2], acc);
      acc = fmaf(v.w, ws2[4 * k4 + 3], acc);
    }
    float o = fmaxf(acc, 0.f);
    ost[wl][lane] = o;           // wave-private; per-wave DS ordering guarantees visibility
    float uacc = uinit;
    const float4* orow = reinterpret_cast<const float4*>(&ost[wl][0]);
#pragma unroll
    for (int k4 = 0; k4 < 16; ++k4) {
      float4 v = orow[k4];
      uacc = fmaf(v.x, w1c[4 * k4 + 0], uacc);
      uacc = fmaf(v.y, w1c[4 * k4 + 1], uacc);
      uacc = fmaf(v.z, w1c[4 * k4 + 2], uacc);
      uacc = fmaf(v.w, w1c[4 * k4 + 3], uacc);
    }
    u[(size_t)n * 64 + lane] = uacc;
  }
}

// ---------------- upd: M_hat[b,r,p] += sum_j relu(u_r[r,j]-u_p[p,j])*W2[j] + b2 ----------
// 512 blocks (batch x 8 r-chunks of 16), 128 threads, 4r x 4p per thread.
__global__ __launch_bounds__(128) void upd_kern(
    const float* __restrict__ uR, const float* __restrict__ uP,
    const float* __restrict__ W2, const float* __restrict__ b2p,
    float* __restrict__ Mhat) {
  __shared__ float sur[16][66];
  __shared__ float sup[128][66];
  __shared__ float sw2[64];
  int b = blockIdx.x >> 3;
  int r0 = (blockIdx.x & 7) * 16;
  int t = threadIdx.x;
  const float* urG = uR + ((size_t)b * 128 + r0) * 64;
#pragma unroll
  for (int s = 0; s < 8; ++s) { int i = t + 128 * s; sur[i >> 6][i & 63] = urG[i]; }
  const float* upG = uP + (size_t)b * 128 * 64;
#pragma unroll 8
  for (int s = 0; s < 64; ++s) { int i = t + 128 * s; sup[i >> 6][i & 63] = upG[i]; }
  if (t < 64) sw2[t] = W2[t];
  __syncthreads();
  int tx = t & 31, ty = t >> 5;
  float acc[4][4] = {};
  for (int j = 0; j < 64; ++j) {
    float w2v = sw2[j];
    float a[4], bb[4];
#pragma unroll
    for (int ii = 0; ii < 4; ++ii) a[ii] = sur[ty + 4 * ii][j];
#pragma unroll
    for (int i = 0; i < 4; ++i) bb[i] = sup[tx + 32 * i][j];
#pragma unroll
    for (int ii = 0; ii < 4; ++ii)
#pragma unroll
      for (int i = 0; i < 4; ++i)
        acc[ii][i] = fmaf(fmaxf(a[ii] - bb[i], 0.f), w2v, acc[ii][i]);
  }
  float b2v = b2p[0];
  float* mrow = Mhat + ((size_t)b * 128 + r0) * 128;
#pragma unroll
  for (int ii = 0; ii < 4; ++ii) {
    int r = ty + 4 * ii;
#pragma unroll
    for (int i = 0; i < 4; ++i) {
      int p = tx + 32 * i;
      mrow[(size_t)r * 128 + p] += acc[ii][i] + b2v;
    }
  }
}

extern "C" void kernel_launch(void* const* d_in, const int* in_sizes, int n_in,
                              void* d_out, int out_size, void* d_ws, size_t ws_size,
                              hipStream_t stream) {
  (void)in_sizes; (void)n_in; (void)out_size; (void)ws_size;
  const float* x_r  = (const float*)d_in[0];
  const int*   ei_r = (const int*)d_in[1];
  const float* ef_r = (const float*)d_in[2];
  const float* x_p  = (const float*)d_in[3];
  const int*   ei_p = (const int*)d_in[4];
  const float* ef_p = (const float*)d_in[5];
  // d_in[6], d_in[7]: masks (all-true) — unused
  const float* g1_Ws = (const float*)d_in[8];
  const float* g1_Wm = (const float*)d_in[9];
  const float* g1_We = (const float*)d_in[10];
  const float* g1_b  = (const float*)d_in[11];
  const float* g2_Ws = (const float*)d_in[12];
  const float* g2_Wm = (const float*)d_in[13];
  const float* g2_We = (const float*)d_in[14];
  const float* g2_b  = (const float*)d_in[15];
  const float* W1 = (const float*)d_in[16];
  const float* b1 = (const float*)d_in[17];
  const float* W2 = (const float*)d_in[18];
  const float* b2 = (const float*)d_in[19];
  float* out = (float*)d_out;

  float* ws = (float*)d_ws;
  float* h_r   = ws;                 // 524288
  float* h_p   = h_r + 524288;       // 524288
  float* Mhat  = h_p + 524288;       // 1048576
  float* M     = Mhat + 1048576;     // 1048576
  float* rfr   = M + 1048576;        // 262144
  float* rfp   = rfr + 262144;       // 262144
  float* u_r   = rfp + 262144;       // 524288
  float* u_p   = u_r + 524288;       // 524288
  float* agg_r = u_p + 524288;       // 524288
  float* agg_p = agg_r + 524288;     // 524288  (contiguous with agg_r)

  // gnn1 on both graphs
  hipMemsetAsync(agg_r, 0, (size_t)2 * 524288 * sizeof(float), stream);
  edge_kern<64><<<1024, 256, 0, stream>>>(x_r, ei_r, ef_r, agg_r,
                                          x_p, ei_p, ef_p, agg_p, g1_Wm, g1_We);
  node1_kern<<<256, 256, 0, stream>>>(x_r, agg_r, h_r, x_p, agg_p, h_p, g1_Ws, g1_b);
  mhat_kern<<<512, 64, 0, stream>>>(h_r, h_p, Mhat);

  for (int it = 0; it < 3; ++it) {
    // folded key = threefry2x32(key=(0,42), count=(0,it))  — host-side, deterministic
    unsigned fk0 = 0u, fk1 = (unsigned)it;
    tf2x32(0u, 42u, fk0, fk1);
    softmax_rng_kern<<<2112, 256, 0, stream>>>(Mhat, M, it == 0 ? out : nullptr,
                                               rfr, fk0, fk1);
    rfp_zero_kern<<<128, 256, 0, stream>>>(M, rfr, rfp, agg_r);
    edge_kern<32><<<1024, 256, 0, stream>>>(rfr, ei_r, ef_r, agg_r,
                                            rfp, ei_p, ef_p, agg_p, g2_Wm, g2_We);
    node2u_kern<<<256, 256, 0, stream>>>(rfr, agg_r, u_r, rfp, agg_p, u_p,
                                         g2_Ws, g2_b, W1, b1);
    upd_kern<<<512, 128, 0, stream>>>(u_r, u_p, W2, b2, Mhat);
  }
  softmax_rng_kern<<<2048, 256, 0, stream>>>(Mhat, nullptr, out + 1048576,
                                             nullptr, 0u, 0u);
}

// Round 3
// 517.820 us; speedup vs baseline: 1.4355x; 1.4355x over previous
//
#include <hip/hip_runtime.h>

// Problem constants
constexpr int kE = 65536, kNTOT = 8192;

// ---------------- threefry2x32 (JAX-exact, 20 rounds) ----------------
__host__ __device__ __forceinline__ void tf_round(unsigned& x0, unsigned& x1, int r) {
  x0 += x1;
  x1 = (x1 << r) | (x1 >> (32 - r));
  x1 ^= x0;
}
__host__ __device__ __forceinline__ void tf2x32(unsigned k0, unsigned k1,
                                                unsigned& x0, unsigned& x1) {
  unsigned ks2 = k0 ^ k1 ^ 0x1BD11BDAu;
  x0 += k0; x1 += k1;
  tf_round(x0,x1,13); tf_round(x0,x1,15); tf_round(x0,x1,26); tf_round(x0,x1,6);
  x0 += k1; x1 += ks2 + 1u;
  tf_round(x0,x1,17); tf_round(x0,x1,29); tf_round(x0,x1,16); tf_round(x0,x1,24);
  x0 += ks2; x1 += k0 + 2u;
  tf_round(x0,x1,13); tf_round(x0,x1,15); tf_round(x0,x1,26); tf_round(x0,x1,6);
  x0 += k0; x1 += k1 + 3u;
  tf_round(x0,x1,17); tf_round(x0,x1,29); tf_round(x0,x1,16); tf_round(x0,x1,24);
  x0 += k1; x1 += ks2 + 4u;
  tf_round(x0,x1,13); tf_round(x0,x1,15); tf_round(x0,x1,26); tf_round(x0,x1,6);
  x0 += ks2; x1 += k0 + 5u;
}

// bits -> N(0,1), replicating jax.random.normal f32 path (partitionable threefry)
__device__ __forceinline__ float bits_to_normal(unsigned bits) {
  float f = __uint_as_float((bits >> 9) | 0x3f800000u) - 1.0f;  // [0,1)
  const float LO = -0.99999994f;
  float u = fmaf(f, 2.0f, LO);
  u = fmaxf(u, LO);
  float w = -log1pf(-u * u);
  float p;
  if (w < 5.0f) {
    w -= 2.5f;
    p = 2.81022636e-08f;
    p = fmaf(p, w, 3.43273939e-07f);
    p = fmaf(p, w, -3.5233877e-06f);
    p = fmaf(p, w, -4.39150654e-06f);
    p = fmaf(p, w, 0.00021858087f);
    p = fmaf(p, w, -0.00125372503f);
    p = fmaf(p, w, -0.00417768164f);
    p = fmaf(p, w, 0.246640727f);
    p = fmaf(p, w, 1.50140941f);
  } else {
    w = sqrtf(w) - 3.0f;
    p = -0.000200214257f;
    p = fmaf(p, w, 0.000100950558f);
    p = fmaf(p, w, 0.00134934322f);
    p = fmaf(p, w, -0.00367342844f);
    p = fmaf(p, w, 0.00573950773f);
    p = fmaf(p, w, -0.0076224613f);
    p = fmaf(p, w, 0.00943887047f);
    p = fmaf(p, w, 1.00167406f);
    p = fmaf(p, w, 2.83297682f);
  }
  return 1.41421356f * (p * u);
}

// ================= CSR build (once per launch; edge_index reused 4x) =================
__global__ __launch_bounds__(256) void hist_kern(const int* __restrict__ eiR,
                                                 const int* __restrict__ eiP,
                                                 int* __restrict__ cntR,
                                                 int* __restrict__ cntP) {
  int i = blockIdx.x * 256 + threadIdx.x;  // 0..131071
  const int* ei = (i < kE) ? eiR : eiP;
  int* cnt = (i < kE) ? cntR : cntP;
  int e = i & (kE - 1);
  atomicAdd(&cnt[ei[kE + e]], 1);
}

// one wave per graph: shuffle-scan 128 chunks of 64
__global__ __launch_bounds__(64) void scan_kern(const int* __restrict__ cntR,
                                                int* __restrict__ rpR, int* __restrict__ offR,
                                                const int* __restrict__ cntP,
                                                int* __restrict__ rpP, int* __restrict__ offP) {
  const int* cnt = blockIdx.x ? cntP : cntR;
  int* rp = blockIdx.x ? rpP : rpR;
  int* off = blockIdx.x ? offP : offR;
  int t = threadIdx.x;
  int run = 0;
  for (int c = 0; c < 128; ++c) {
    int i = c * 64 + t;
    int v = cnt[i];
    int x = v;
#pragma unroll
    for (int o = 1; o < 64; o <<= 1) {
      int y = __shfl_up(x, o);
      if (t >= o) x += y;
    }
    int excl = run + x - v;
    rp[i] = excl;
    off[i] = excl;
    run += __shfl(x, 63);
  }
  if (t == 0) rp[kNTOT] = kE;
}

__global__ __launch_bounds__(256) void scatter_kern(
    const int* __restrict__ eiR, const int* __restrict__ eiP,
    int* __restrict__ offR, int* __restrict__ offP,
    int* __restrict__ permR, int* __restrict__ permP,
    int* __restrict__ srcsR, int* __restrict__ srcsP) {
  int i = blockIdx.x * 256 + threadIdx.x;
  const int* ei = (i < kE) ? eiR : eiP;
  int* off = (i < kE) ? offR : offP;
  int* perm = (i < kE) ? permR : permP;
  int* srcs = (i < kE) ? srcsR : srcsP;
  int e = i & (kE - 1);
  int dst = ei[kE + e];
  int pos = atomicAdd(&off[dst], 1);
  perm[pos] = e;
  srcs[pos] = ei[e];
}

// ================= msg GEMM: msg[i] = relu(x[srcs[i]]@Wm + ef[perm[i]]@We) ========
// 64 edges x 64 outs per block, K = KX + 16 unified. Edges in CSR-sorted order.
template <int KX>
__global__ __launch_bounds__(256) void msg_gemm(
    const float* __restrict__ x, const float* __restrict__ ef,
    const int* __restrict__ srcs, const int* __restrict__ perm,
    float* __restrict__ msg,
    const float* __restrict__ Wm, const float* __restrict__ We) {
  constexpr int KT = KX + 16;
  __shared__ float sA[KT][68];   // transposed A-tile: [k][edge]
  __shared__ float sW[KT][68];   // [k][j]
  int i0 = blockIdx.x * 64;
  int t = threadIdx.x;
  // stage W (KT*64 floats, float4 each)
#pragma unroll
  for (int idx = 0; idx < KT * 64 / 1024; ++idx) {
    int q = t * 4 + idx * 1024;
    int k = q >> 6, j = q & 63;
    const float* sp = (k < KX) ? (Wm + k * 64 + j) : (We + (k - KX) * 64 + j);
    float4 v = *reinterpret_cast<const float4*>(sp);
    *reinterpret_cast<float4*>(&sW[k][j]) = v;
  }
  // stage A transposed (gathered rows)
#pragma unroll
  for (int idx = 0; idx < KT * 64 / 1024; ++idx) {
    int q = t * 4 + idx * 1024;
    int r = q / KT;
    int k = q % KT;   // 4-aligned
    const float* rp = (k < KX) ? (x + (size_t)srcs[i0 + r] * KX + k)
                               : (ef + (size_t)perm[i0 + r] * 16 + (k - KX));
    float4 v = *reinterpret_cast<const float4*>(rp);
    sA[k + 0][r] = v.x; sA[k + 1][r] = v.y; sA[k + 2][r] = v.z; sA[k + 3][r] = v.w;
  }
  __syncthreads();
  int tn = (t & 15) * 4;   // edge sub-tile
  int tj = (t >> 4) * 4;   // out sub-tile
  float acc[4][4] = {};
#pragma unroll 8
  for (int k = 0; k < KT; ++k) {
    float4 a = *reinterpret_cast<const float4*>(&sA[k][tn]);
    float4 b = *reinterpret_cast<const float4*>(&sW[k][tj]);
    acc[0][0] = fmaf(a.x, b.x, acc[0][0]); acc[0][1] = fmaf(a.x, b.y, acc[0][1]);
    acc[0][2] = fmaf(a.x, b.z, acc[0][2]); acc[0][3] = fmaf(a.x, b.w, acc[0][3]);
    acc[1][0] = fmaf(a.y, b.x, acc[1][0]); acc[1][1] = fmaf(a.y, b.y, acc[1][1]);
    acc[1][2] = fmaf(a.y, b.z, acc[1][2]); acc[1][3] = fmaf(a.y, b.w, acc[1][3]);
    acc[2][0] = fmaf(a.z, b.x, acc[2][0]); acc[2][1] = fmaf(a.z, b.y, acc[2][1]);
    acc[2][2] = fmaf(a.z, b.z, acc[2][2]); acc[2][3] = fmaf(a.z, b.w, acc[2][3]);
    acc[3][0] = fmaf(a.w, b.x, acc[3][0]); acc[3][1] = fmaf(a.w, b.y, acc[3][1]);
    acc[3][2] = fmaf(a.w, b.z, acc[3][2]); acc[3][3] = fmaf(a.w, b.w, acc[3][3]);
  }
#pragma unroll
  for (int i = 0; i < 4; ++i) {
    float4 o;
    o.x = fmaxf(acc[i][0], 0.f); o.y = fmaxf(acc[i][1], 0.f);
    o.z = fmaxf(acc[i][2], 0.f); o.w = fmaxf(acc[i][3], 0.f);
    *reinterpret_cast<float4*>(&msg[(size_t)(i0 + tn + i) * 64 + tj]) = o;
  }
}

// ================= agg[d] = sum of contiguous msg rows rp[d]..rp[d+1] ================
__global__ __launch_bounds__(256) void agg_kern(const float* __restrict__ msg,
                                                const int* __restrict__ rp,
                                                float* __restrict__ agg) {
  int lane = threadIdx.x & 63;
  int d = blockIdx.x * 4 + (threadIdx.x >> 6);  // 0..8191
  int s = rp[d], e = rp[d + 1];
  float acc = 0.f;
  for (int i = s; i < e; ++i) acc += msg[(size_t)i * 64 + lane];
  agg[(size_t)d * 64 + lane] = acc;
}

// ---------------- gnn1 node kernel: h = relu(x@Ws + agg + b) ----------------
__global__ __launch_bounds__(256) void node1_kern(
    const float* __restrict__ xR, const float* __restrict__ aggR, float* __restrict__ hR,
    const float* __restrict__ xP, const float* __restrict__ aggP, float* __restrict__ hP,
    const float* __restrict__ Ws, const float* __restrict__ bias) {
  int lane = threadIdx.x & 63;
  int wv = blockIdx.x * 4 + (threadIdx.x >> 6);  // 0..1023
  float wcol[64];
#pragma unroll
  for (int k = 0; k < 64; ++k) wcol[k] = Ws[k * 64 + lane];
  float bv = bias[lane];
  const float* x; const float* agg; float* h; int base;
  if (wv < 512) { x = xR; agg = aggR; h = hR; base = wv * 16; }
  else { x = xP; agg = aggP; h = hP; base = (wv - 512) * 16; }
  for (int n = base; n < base + 16; ++n) {
    float acc = agg[(size_t)n * 64 + lane] + bv;
    const float4* xr = reinterpret_cast<const float4*>(x + (size_t)n * 64);
#pragma unroll
    for (int k4 = 0; k4 < 16; ++k4) {
      float4 v = xr[k4];
      acc = fmaf(v.x, wcol[4 * k4 + 0], acc);
      acc = fmaf(v.y, wcol[4 * k4 + 1], acc);
      acc = fmaf(v.z, wcol[4 * k4 + 2], acc);
      acc = fmaf(v.w, wcol[4 * k4 + 3], acc);
    }
    h[(size_t)n * 64 + lane] = fmaxf(acc, 0.f);
  }
}

// ---------------- M_hat[b,r,p] = sum_d h_r[b,r,d]*h_p[b,p,d] ----------------
__global__ __launch_bounds__(64) void mhat_kern(const float* __restrict__ hR,
                                                const float* __restrict__ hP,
                                                float* __restrict__ Mhat) {
  __shared__ float hr[16][66];
  __shared__ float hp[128][66];
  int b = blockIdx.x >> 3;
  int r0 = (blockIdx.x & 7) * 16;
  int t = threadIdx.x;
  const float* hrG = hR + ((size_t)b * 128 + r0) * 64;
#pragma unroll
  for (int s = 0; s < 16; ++s) { int i = t + 64 * s; hr[i >> 6][i & 63] = hrG[i]; }
  const float* hpG = hP + (size_t)b * 128 * 64;
#pragma unroll 8
  for (int s = 0; s < 128; ++s) { int i = t + 64 * s; hp[i >> 6][i & 63] = hpG[i]; }
  __syncthreads();
  int tx = t & 31;
  int ty = t >> 5;
  float acc[8][4] = {};
  for (int d = 0; d < 64; ++d) {
    float a[8], bb[4];
#pragma unroll
    for (int ii = 0; ii < 8; ++ii) a[ii] = hr[ty + 2 * ii][d];
#pragma unroll
    for (int i = 0; i < 4; ++i) bb[i] = hp[tx + 32 * i][d];
#pragma unroll
    for (int ii = 0; ii < 8; ++ii)
#pragma unroll
      for (int i = 0; i < 4; ++i) acc[ii][i] = fmaf(a[ii], bb[i], acc[ii][i]);
  }
  float* outp = Mhat + ((size_t)b * 128 + r0) * 128;
#pragma unroll
  for (int ii = 0; ii < 8; ++ii)
#pragma unroll
    for (int i = 0; i < 4; ++i)
      outp[(size_t)(ty + 2 * ii) * 128 + tx + 32 * i] = acc[ii][i];
}

// ---------------- softmax rows of 128 (+ fused threefry RNG blocks) ----------------
__global__ __launch_bounds__(256) void softmax_rng_kern(
    const float* __restrict__ Mhat, float* __restrict__ Mout, float* __restrict__ outDst,
    float* __restrict__ rf, unsigned fk0, unsigned fk1) {
  if (blockIdx.x < 2048) {
    int lane = threadIdx.x & 63;
    int row = blockIdx.x * 4 + (threadIdx.x >> 6);
    const float2* src = reinterpret_cast<const float2*>(Mhat + (size_t)row * 128);
    float2 v = src[lane];
    float mx = fmaxf(v.x, v.y);
#pragma unroll
    for (int o = 32; o > 0; o >>= 1) mx = fmaxf(mx, __shfl_xor(mx, o));
    float e0 = __expf(v.x - mx), e1 = __expf(v.y - mx);
    float s = e0 + e1;
#pragma unroll
    for (int o = 32; o > 0; o >>= 1) s += __shfl_xor(s, o);
    float inv = 1.0f / s;
    float2 r2; r2.x = e0 * inv; r2.y = e1 * inv;
    if (Mout)  reinterpret_cast<float2*>(Mout + (size_t)row * 128)[lane] = r2;
    if (outDst) reinterpret_cast<float2*>(outDst + (size_t)row * 128)[lane] = r2;
  } else {
    int ti = (blockIdx.x - 2048) * 256 + threadIdx.x;  // 0..16383
#pragma unroll
    for (int q = 0; q < 16; ++q) {
      unsigned i = (unsigned)ti + q * 16384u;   // 0..262143
      unsigned x0 = 0u, x1 = i;                 // counter (hi, lo) = (0, i)
      tf2x32(fk0, fk1, x0, x1);
      rf[i] = bits_to_normal(x0 ^ x1);
    }
  }
}

// ---------------- rf_p[b,p,i] = sum_r M[b,r,p]*rf_r[b,r,i] ----------------
__global__ __launch_bounds__(256) void rfp_kern(
    const float* __restrict__ M, const float* __restrict__ rf, float* __restrict__ rfp) {
  __shared__ float rr[128][32];
  int b = blockIdx.x;
  int t = threadIdx.x;
  const float* rfG = rf + (size_t)b * 128 * 32;
#pragma unroll
  for (int s = 0; s < 16; ++s) { int i = t + 256 * s; rr[i >> 5][i & 31] = rfG[i]; }
  __syncthreads();
  int p = t >> 1, hf = t & 1;
  float acc[16] = {};
  const float* Mb = M + (size_t)b * 16384 + p;
  for (int r = 0; r < 128; ++r) {
    float m = Mb[(size_t)r * 128];
#pragma unroll
    for (int i = 0; i < 16; ++i) acc[i] = fmaf(m, rr[r][hf * 16 + i], acc[i]);
  }
  float4* dst = reinterpret_cast<float4*>(rfp + ((size_t)b * 128 + p) * 32 + hf * 16);
  dst[0] = make_float4(acc[0], acc[1], acc[2], acc[3]);
  dst[1] = make_float4(acc[4], acc[5], acc[6], acc[7]);
  dst[2] = make_float4(acc[8], acc[9], acc[10], acc[11]);
  dst[3] = make_float4(acc[12], acc[13], acc[14], acc[15]);
}

// ---------------- gnn2 node + @W1 fusion ----------------
__global__ __launch_bounds__(256) void node2u_kern(
    const float* __restrict__ rfR, const float* __restrict__ aggR, float* __restrict__ uR,
    const float* __restrict__ rfP, const float* __restrict__ aggP, float* __restrict__ uP,
    const float* __restrict__ Ws2, const float* __restrict__ b2g,
    const float* __restrict__ W1, const float* __restrict__ b1) {
  __shared__ float ost[4][64];
  int lane = threadIdx.x & 63;
  int wl = threadIdx.x >> 6;
  int wv = blockIdx.x * 4 + wl;
  float ws2[32];
#pragma unroll
  for (int k = 0; k < 32; ++k) ws2[k] = Ws2[k * 64 + lane];
  float w1c[64];
#pragma unroll
  for (int k = 0; k < 64; ++k) w1c[k] = W1[k * 64 + lane];
  float bgv = b2g[lane];
  const float* rf; const float* agg; float* u; float uinit; int base;
  if (wv < 512) { rf = rfR; agg = aggR; u = uR; base = wv * 16; uinit = b1[lane]; }
  else { rf = rfP; agg = aggP; u = uP; base = (wv - 512) * 16; uinit = 0.f; }
  for (int n = base; n < base + 16; ++n) {
    float acc = agg[(size_t)n * 64 + lane] + bgv;
    const float4* xr = reinterpret_cast<const float4*>(rf + (size_t)n * 32);
#pragma unroll
    for (int k4 = 0; k4 < 8; ++k4) {
      float4 v = xr[k4];
      acc = fmaf(v.x, ws2[4 * k4 + 0], acc);
      acc = fmaf(v.y, ws2[4 * k4 + 1], acc);
      acc = fmaf(v.z, ws2[4 * k4 + 2], acc);
      acc = fmaf(v.w, ws2[4 * k4 + 3], acc);
    }
    float o = fmaxf(acc, 0.f);
    ost[wl][lane] = o;
    float uacc = uinit;
    const float4* orow = reinterpret_cast<const float4*>(&ost[wl][0]);
#pragma unroll
    for (int k4 = 0; k4 < 16; ++k4) {
      float4 v = orow[k4];
      uacc = fmaf(v.x, w1c[4 * k4 + 0], uacc);
      uacc = fmaf(v.y, w1c[4 * k4 + 1], uacc);
      uacc = fmaf(v.z, w1c[4 * k4 + 2], uacc);
      uacc = fmaf(v.w, w1c[4 * k4 + 3], uacc);
    }
    u[(size_t)n * 64 + lane] = uacc;
  }
}

// ---------------- upd: M_hat[b,r,p] += sum_j relu(u_r[r,j]-u_p[p,j])*W2[j] + b2 ------
__global__ __launch_bounds__(128) void upd_kern(
    const float* __restrict__ uR, const float* __restrict__ uP,
    const float* __restrict__ W2, const float* __restrict__ b2p,
    float* __restrict__ Mhat) {
  __shared__ float sur[16][66];
  __shared__ float sup[128][66];
  __shared__ float sw2[64];
  int b = blockIdx.x >> 3;
  int r0 = (blockIdx.x & 7) * 16;
  int t = threadIdx.x;
  const float* urG = uR + ((size_t)b * 128 + r0) * 64;
#pragma unroll
  for (int s = 0; s < 8; ++s) { int i = t + 128 * s; sur[i >> 6][i & 63] = urG[i]; }
  const float* upG = uP + (size_t)b * 128 * 64;
#pragma unroll 8
  for (int s = 0; s < 64; ++s) { int i = t + 128 * s; sup[i >> 6][i & 63] = upG[i]; }
  if (t < 64) sw2[t] = W2[t];
  __syncthreads();
  int tx = t & 31, ty = t >> 5;
  float acc[4][4] = {};
  for (int j = 0; j < 64; ++j) {
    float w2v = sw2[j];
    float a[4], bb[4];
#pragma unroll
    for (int ii = 0; ii < 4; ++ii) a[ii] = sur[ty + 4 * ii][j];
#pragma unroll
    for (int i = 0; i < 4; ++i) bb[i] = sup[tx + 32 * i][j];
#pragma unroll
    for (int ii = 0; ii < 4; ++ii)
#pragma unroll
      for (int i = 0; i < 4; ++i)
        acc[ii][i] = fmaf(fmaxf(a[ii] - bb[i], 0.f), w2v, acc[ii][i]);
  }
  float b2v = b2p[0];
  float* mrow = Mhat + ((size_t)b * 128 + r0) * 128;
#pragma unroll
  for (int ii = 0; ii < 4; ++ii) {
    int r = ty + 4 * ii;
#pragma unroll
    for (int i = 0; i < 4; ++i) {
      int p = tx + 32 * i;
      mrow[(size_t)r * 128 + p] += acc[ii][i] + b2v;
    }
  }
}

extern "C" void kernel_launch(void* const* d_in, const int* in_sizes, int n_in,
                              void* d_out, int out_size, void* d_ws, size_t ws_size,
                              hipStream_t stream) {
  (void)in_sizes; (void)n_in; (void)out_size; (void)ws_size;
  const float* x_r  = (const float*)d_in[0];
  const int*   ei_r = (const int*)d_in[1];
  const float* ef_r = (const float*)d_in[2];
  const float* x_p  = (const float*)d_in[3];
  const int*   ei_p = (const int*)d_in[4];
  const float* ef_p = (const float*)d_in[5];
  const float* g1_Ws = (const float*)d_in[8];
  const float* g1_Wm = (const float*)d_in[9];
  const float* g1_We = (const float*)d_in[10];
  const float* g1_b  = (const float*)d_in[11];
  const float* g2_Ws = (const float*)d_in[12];
  const float* g2_Wm = (const float*)d_in[13];
  const float* g2_We = (const float*)d_in[14];
  const float* g2_b  = (const float*)d_in[15];
  const float* W1 = (const float*)d_in[16];
  const float* b1 = (const float*)d_in[17];
  const float* W2 = (const float*)d_in[18];
  const float* b2 = (const float*)d_in[19];
  float* out = (float*)d_out;

  float* ws = (float*)d_ws;
  float* h_r   = ws;                 // 524288
  float* h_p   = h_r + 524288;       // 524288
  float* Mhat  = h_p + 524288;       // 1048576
  float* M     = Mhat + 1048576;     // 1048576
  float* rfr   = M + 1048576;        // 262144
  float* rfp   = rfr + 262144;       // 262144
  float* u_r   = rfp + 262144;       // 524288
  float* u_p   = u_r + 524288;       // 524288
  float* agg_r = u_p + 524288;       // 524288
  float* agg_p = agg_r + 524288;     // 524288
  float* msg   = agg_p + 524288;     // 4194304 (shared by both graphs, serialized)
  int* ib      = (int*)(msg + 4194304);
  int* cnt_r  = ib;                  // 8192
  int* cnt_p  = cnt_r + 8192;        // 8192
  int* off_r  = cnt_p + 8192;        // 8192
  int* off_p  = off_r + 8192;        // 8192
  int* rp_r   = off_p + 8192;        // 8193
  int* rp_p   = rp_r + 8193;         // 8193
  int* perm_r = rp_p + 8193;         // 65536
  int* perm_p = perm_r + 65536;      // 65536
  int* srcs_r = perm_p + 65536;      // 65536
  int* srcs_p = srcs_r + 65536;      // 65536

  // ---- CSR build (once; reused by all 4 message passes) ----
  hipMemsetAsync(cnt_r, 0, 2 * 8192 * sizeof(int), stream);
  hist_kern<<<512, 256, 0, stream>>>(ei_r, ei_p, cnt_r, cnt_p);
  scan_kern<<<2, 64, 0, stream>>>(cnt_r, rp_r, off_r, cnt_p, rp_p, off_p);
  scatter_kern<<<512, 256, 0, stream>>>(ei_r, ei_p, off_r, off_p,
                                        perm_r, perm_p, srcs_r, srcs_p);

  // ---- gnn1 ----
  msg_gemm<64><<<1024, 256, 0, stream>>>(x_r, ef_r, srcs_r, perm_r, msg, g1_Wm, g1_We);
  agg_kern<<<2048, 256, 0, stream>>>(msg, rp_r, agg_r);
  msg_gemm<64><<<1024, 256, 0, stream>>>(x_p, ef_p, srcs_p, perm_p, msg, g1_Wm, g1_We);
  agg_kern<<<2048, 256, 0, stream>>>(msg, rp_p, agg_p);
  node1_kern<<<256, 256, 0, stream>>>(x_r, agg_r, h_r, x_p, agg_p, h_p, g1_Ws, g1_b);
  mhat_kern<<<512, 64, 0, stream>>>(h_r, h_p, Mhat);

  for (int it = 0; it < 3; ++it) {
    unsigned fk0 = 0u, fk1 = (unsigned)it;
    tf2x32(0u, 42u, fk0, fk1);
    softmax_rng_kern<<<2112, 256, 0, stream>>>(Mhat, M, it == 0 ? out : nullptr,
                                               rfr, fk0, fk1);
    rfp_kern<<<64, 256, 0, stream>>>(M, rfr, rfp);
    msg_gemm<32><<<1024, 256, 0, stream>>>(rfr, ef_r, srcs_r, perm_r, msg, g2_Wm, g2_We);
    agg_kern<<<2048, 256, 0, stream>>>(msg, rp_r, agg_r);
    msg_gemm<32><<<1024, 256, 0, stream>>>(rfp, ef_p, srcs_p, perm_p, msg, g2_Wm, g2_We);
    agg_kern<<<2048, 256, 0, stream>>>(msg, rp_p, agg_p);
    node2u_kern<<<256, 256, 0, stream>>>(rfr, agg_r, u_r, rfp, agg_p, u_p,
                                         g2_Ws, g2_b, W1, b1);
    upd_kern<<<512, 128, 0, stream>>>(u_r, u_p, W2, b2, Mhat);
  }
  softmax_rng_kern<<<2048, 256, 0, stream>>>(Mhat, nullptr, out + 1048576,
                                             nullptr, 0u, 0u);
}